// Round 7
// baseline (434.080 us; speedup 1.0000x reference)
//
#include <hip/hip_runtime.h>

#define N_NODES 50000
#define N_EDGES 800000
#define D 128
#define NLAYER 4
#define NGRAPH 128
#define GDIM (5 * D) // 640
#define NBUCK 196    // dst>>8 buckets (50000/256)

typedef __attribute__((ext_vector_type(8))) short bf16x8;
typedef __attribute__((ext_vector_type(4))) float f32x4;

__device__ __forceinline__ float b2f(unsigned short u) {
    return __uint_as_float(((unsigned)u) << 16);
}
__device__ __forceinline__ unsigned short f2b(float f) {
    unsigned u = __float_as_uint(f);
    unsigned r = (u + 0x7fffu + ((u >> 16) & 1u)) >> 16; // round-to-nearest-even
    return (unsigned short)r;
}

// ---------------- CSR build ----------------

__global__ void k_count(const int* __restrict__ edst, int* __restrict__ cnt) {
    int e = blockIdx.x * 256 + threadIdx.x;
    if (e < N_EDGES) atomicAdd(&cnt[edst[e]], 1);
}

__global__ void k_dinv(const int* __restrict__ cnt, float* __restrict__ dinv) {
    int i = blockIdx.x * 256 + threadIdx.x;
    if (i < N_NODES) dinv[i] = 1.f / sqrtf((float)(cnt[i] + 1)); // +1 self-loop
}

__global__ void k_scanA(const int* __restrict__ cnt, int* __restrict__ offs,
                        int* __restrict__ chunkSum) {
    __shared__ int lds[256];
    int tid = threadIdx.x;
    int base = blockIdx.x * 1024 + tid * 4;
    int v[4];
    int s = 0;
#pragma unroll
    for (int j = 0; j < 4; ++j) {
        int idx = base + j;
        v[j] = (idx < N_NODES) ? cnt[idx] : 0;
        s += v[j];
    }
    lds[tid] = s;
    __syncthreads();
    int t = s;
    for (int off = 1; off < 256; off <<= 1) {
        int add = (tid >= off) ? lds[tid - off] : 0;
        __syncthreads();
        t += add;
        lds[tid] = t;
        __syncthreads();
    }
    int run = t - s;
#pragma unroll
    for (int j = 0; j < 4; ++j) {
        int idx = base + j;
        if (idx < N_NODES) offs[idx] = run;
        run += v[j];
    }
    if (tid == 255) chunkSum[blockIdx.x] = t;
}

__global__ void k_scanB(const int* __restrict__ chunkSum, int* __restrict__ chunkOff,
                        int nc) {
    __shared__ int lds[64];
    int tid = threadIdx.x;
    int v = (tid < nc) ? chunkSum[tid] : 0;
    lds[tid] = v;
    __syncthreads();
    int t = v;
    for (int off = 1; off < 64; off <<= 1) {
        int add = (tid >= off) ? lds[tid - off] : 0;
        __syncthreads();
        t += add;
        lds[tid] = t;
        __syncthreads();
    }
    if (tid < nc) chunkOff[tid] = t - v;
}

__global__ void k_scanC(int* __restrict__ offs, const int* __restrict__ chunkOff) {
    int i = blockIdx.x * 256 + threadIdx.x;
    if (i < N_NODES) offs[i] += chunkOff[i >> 10];
}

// btail[b] = offs[b*256] (start of bucket b's CSR window)
__global__ void k_btail(const int* __restrict__ offs, int* __restrict__ btail) {
    int b = threadIdx.x;
    if (b < NBUCK) btail[b] = offs[b << 8];
}

// Pass 1: block-aggregated bucket scatter. 4096 edges/block, LDS histogram,
// one ranged atomicAdd per (block,bucket), then write (src,dst) runs.
__global__ __launch_bounds__(256) void k_bucket(
    const int* __restrict__ esrc, const int* __restrict__ edst,
    int* __restrict__ btail, int2* __restrict__ ebuf) {
    __shared__ int hcnt[NBUCK];
    __shared__ int hbase[NBUCK];
    int t = threadIdx.x;
    for (int i = t; i < NBUCK; i += 256) hcnt[i] = 0;
    __syncthreads();
    int e0 = blockIdx.x * 4096 + t;
#pragma unroll
    for (int i = 0; i < 16; ++i) {
        int e = e0 + i * 256;
        if (e < N_EDGES) atomicAdd(&hcnt[edst[e] >> 8], 1);
    }
    __syncthreads();
    for (int i = t; i < NBUCK; i += 256) {
        int c = hcnt[i];
        if (c > 0) hbase[i] = atomicAdd(&btail[i], c);
        hcnt[i] = 0;
    }
    __syncthreads();
#pragma unroll
    for (int i = 0; i < 16; ++i) {
        int e = e0 + i * 256;
        if (e < N_EDGES) {
            int s = esrc[e], d = edst[e];
            int b = d >> 8;
            int p = atomicAdd(&hcnt[b], 1);
            ebuf[hbase[b] + p] = make_int2(s, d);
        }
    }
}

// Pass 2: bucket-ordered edges -> CSR scatter within ~16KB windows (L2-local)
__global__ void k_fill2(const int2* __restrict__ ebuf, const int* __restrict__ offs,
                        int* __restrict__ fillp, int* __restrict__ csrs) {
    int p = blockIdx.x * 256 + threadIdx.x;
    if (p >= N_EDGES) return;
    int2 sd = ebuf[p];
    int q = atomicAdd(&fillp[sd.y], 1);
    csrs[offs[sd.y] + q] = sd.x;
}

// ---------------- pack 5 weight matrices into MFMA B-frag layout (bf16) --------

__global__ void k_packW(const float* __restrict__ Wn, const float* __restrict__ convW,
                        unsigned short* __restrict__ Wpack) {
    int tid = blockIdx.x * 256 + threadIdx.x;
    if (tid >= 5 * 16384) return;
    int m = tid >> 14;
    int rem = tid & 16383;
    int ct = rem >> 11, kc = (rem >> 9) & 3, l = (rem >> 3) & 63, j = rem & 7;
    int k = kc * 32 + ((l >> 4) * 8) + j;
    int n = ct * 16 + (l & 15);
    const float* src = (m == 0) ? Wn : (convW + (size_t)(m - 1) * 16384);
    Wpack[tid] = f2b(src[k * 128 + n]);
}

// ---------------- T[256,128] = relu(id_emb) @ Wn_bottom ----------------

__global__ __launch_bounds__(256) void k_idT(const float* __restrict__ id_emb,
                                             const float* __restrict__ Wn,
                                             float* __restrict__ T) {
    int t = threadIdx.x;
    int d = t & 127;
    int r = blockIdx.x * 2 + (t >> 7);
    float acc = 0.f;
    for (int k = 0; k < 128; ++k)
        acc = fmaf(fmaxf(id_emb[r * 128 + k], 0.f), Wn[(128 + k) * 128 + d], acc);
    T[r * 128 + d] = acc;
}

// ---------------- MFMA encoder: A16 = bf16(relu(posrelu @ Wn_top + T[id] + bn)) ----

__global__ __launch_bounds__(256) void k_encoder(
    const float* __restrict__ pos, const int* __restrict__ idfeat,
    const float* __restrict__ Wp, const float* __restrict__ bp,
    const unsigned short* __restrict__ WpackE, const float* __restrict__ bn,
    const float* __restrict__ T, unsigned short* __restrict__ A16) {
    __shared__ unsigned short feat[64 * 128]; // 16KB, swizzled
    __shared__ float posl[192];
    int t = threadIdx.x;
    int base = blockIdx.x * 64;
    int avail = N_NODES - base;
    if (t < 192) {
        int idx = base * 3 + t;
        posl[t] = (idx < N_NODES * 3) ? pos[idx] : 0.f;
    }
    __syncthreads();
#pragma unroll
    for (int i = 0; i < 4; ++i) {
        int gid = t + i * 256;
        int row = gid >> 4, kg = gid & 15;
        unsigned short u[8];
        if (row < avail) {
            float p0 = posl[row * 3], p1 = posl[row * 3 + 1], p2 = posl[row * 3 + 2];
#pragma unroll
            for (int j = 0; j < 8; ++j) {
                int d = kg * 8 + j;
                float v = fmaf(p0, Wp[d], fmaf(p1, Wp[128 + d], fmaf(p2, Wp[256 + d], bp[d])));
                u[j] = f2b(fmaxf(v, 0.f));
            }
        } else {
#pragma unroll
            for (int j = 0; j < 8; ++j) u[j] = 0;
        }
        char* dst = (char*)feat + row * 256 + ((kg * 16) ^ ((row & 7) << 4));
        *(uint4*)dst = *(uint4*)u;
    }
    __syncthreads();
    int wid = t >> 6, l = t & 63;
    int r0 = wid * 16;
    f32x4 acc[8];
#pragma unroll
    for (int ct = 0; ct < 8; ++ct) acc[ct] = (f32x4){0.f, 0.f, 0.f, 0.f};
    const bf16x8* wp = (const bf16x8*)WpackE;
#pragma unroll
    for (int kc = 0; kc < 4; ++kc) {
        int row = r0 + (l & 15);
        const char* ap = (const char*)feat + row * 256 +
                         ((kc * 64 + ((l >> 4) * 16)) ^ ((row & 7) << 4));
        bf16x8 afrag = *(const bf16x8*)ap;
#pragma unroll
        for (int ct = 0; ct < 8; ++ct) {
            bf16x8 bfrag = wp[(ct * 4 + kc) * 64 + l];
            acc[ct] = __builtin_amdgcn_mfma_f32_16x16x32_bf16(afrag, bfrag, acc[ct], 0, 0, 0);
        }
    }
    int subrow = (l >> 4) * 4, col0 = l & 15;
    int ids[4];
#pragma unroll
    for (int i = 0; i < 4; ++i) {
        int node = base + r0 + subrow + i;
        ids[i] = (node < N_NODES) ? idfeat[node] : 0;
    }
#pragma unroll
    for (int ct = 0; ct < 8; ++ct) {
        int col = ct * 16 + col0;
        float bcol = bn[col];
#pragma unroll
        for (int i = 0; i < 4; ++i) {
            int node = base + r0 + subrow + i;
            if (node < N_NODES) {
                float v = acc[ct][i] + bcol + T[ids[i] * 128 + col];
                A16[(size_t)node * 128 + col] = f2b(fmaxf(v, 0.f));
            }
        }
    }
}

// ---------------- MFMA GEMM: Bb[N,128](bf16) = A16[N,128](bf16) @ W ----------

__global__ __launch_bounds__(256) void k_gemm(
    const unsigned short* __restrict__ H16, const unsigned short* __restrict__ WpackL,
    unsigned short* __restrict__ Bb) {
    __shared__ unsigned short feat[64 * 128]; // 16KB, swizzled
    int t = threadIdx.x;
    int base = blockIdx.x * 64;
    int avail = N_NODES - base;
#pragma unroll
    for (int i = 0; i < 4; ++i) {
        int gid = t + i * 256;
        int row = gid >> 4, kg = gid & 15;
        uint4 v = make_uint4(0, 0, 0, 0);
        if (row < avail)
            v = *(const uint4*)&H16[(size_t)(base + row) * 128 + kg * 8];
        char* dst = (char*)feat + row * 256 + ((kg * 16) ^ ((row & 7) << 4));
        *(uint4*)dst = v;
    }
    __syncthreads();
    int wid = t >> 6, l = t & 63;
    int r0 = wid * 16;
    f32x4 acc[8];
#pragma unroll
    for (int ct = 0; ct < 8; ++ct) acc[ct] = (f32x4){0.f, 0.f, 0.f, 0.f};
    const bf16x8* wp = (const bf16x8*)WpackL;
#pragma unroll
    for (int kc = 0; kc < 4; ++kc) {
        int row = r0 + (l & 15);
        const char* ap = (const char*)feat + row * 256 +
                         ((kc * 64 + ((l >> 4) * 16)) ^ ((row & 7) << 4));
        bf16x8 afrag = *(const bf16x8*)ap;
#pragma unroll
        for (int ct = 0; ct < 8; ++ct) {
            bf16x8 bfrag = wp[(ct * 4 + kc) * 64 + l];
            acc[ct] = __builtin_amdgcn_mfma_f32_16x16x32_bf16(afrag, bfrag, acc[ct], 0, 0, 0);
        }
    }
    int subrow = (l >> 4) * 4, col0 = l & 15;
#pragma unroll
    for (int ct = 0; ct < 8; ++ct) {
#pragma unroll
        for (int i = 0; i < 4; ++i) {
            int node = base + r0 + subrow + i;
            if (node < N_NODES)
                Bb[(size_t)node * 128 + ct * 16 + col0] = f2b(acc[ct][i]);
        }
    }
}

// ---------------- GCN aggregate (bf16 msgs, fp32 accumulate, bf16 out) --------

__global__ __launch_bounds__(256) void k_gather(
    const unsigned short* __restrict__ B, unsigned short* __restrict__ A16,
    const int* __restrict__ offs, const int* __restrict__ cnt,
    const int* __restrict__ csrs, const float* __restrict__ dinv,
    const float* __restrict__ bias) {
    int lane = threadIdx.x & 63;
    int sub = lane >> 5;
    int l = lane & 31;
    int node = blockIdx.x * 8 + (threadIdx.x >> 6) * 2 + sub;
    if (node >= N_NODES) return;
    int start = offs[node];
    int c = cnt[node];
    float di = dinv[node];
    float sw = di * di;
    const ushort4* B4 = (const ushort4*)B; // 32 ushort4 per row
    ushort4 sv = B4[(size_t)node * 32 + l];
    float4 acc;
    acc.x = sw * b2f(sv.x);
    acc.y = sw * b2f(sv.y);
    acc.z = sw * b2f(sv.z);
    acc.w = sw * b2f(sv.w);
#pragma unroll 2
    for (int j = 0; j < c; ++j) {
        int s = csrs[start + j];
        float w = di * dinv[s];
        ushort4 v = B4[(size_t)s * 32 + l];
        acc.x = fmaf(w, b2f(v.x), acc.x);
        acc.y = fmaf(w, b2f(v.y), acc.y);
        acc.z = fmaf(w, b2f(v.z), acc.z);
        acc.w = fmaf(w, b2f(v.w), acc.w);
    }
    float4 bb = ((const float4*)bias)[l];
    ushort4 o;
    o.x = f2b(fmaxf(acc.x + bb.x, 0.f));
    o.y = f2b(fmaxf(acc.y + bb.y, 0.f));
    o.z = f2b(fmaxf(acc.z + bb.z, 0.f));
    o.w = f2b(fmaxf(acc.w + bb.w, 0.f));
    ((ushort4*)(A16 + (size_t)node * 128))[l] = o;
}

// ---------------- segment max over bf16 A (batch sorted) ----------------

__global__ void k_segmax(const unsigned short* __restrict__ A16,
                         float* __restrict__ gbuf,
                         const int* __restrict__ batch, int off) {
    int gid = blockIdx.x * blockDim.x + threadIdx.x;
    int d = gid & 127;
    int chunk = gid >> 7;
    int n0 = chunk * 32;
    if (n0 >= N_NODES) return;
    int nend = n0 + 32;
    if (nend > N_NODES) nend = N_NODES;
    float m = 0.f;
    int curg = batch[n0];
    for (int node = n0; node < nend; ++node) {
        int g = batch[node];
        if (g != curg) {
            atomicMax((int*)&gbuf[curg * GDIM + off + d], __float_as_int(m));
            curg = g;
            m = 0.f;
        }
        m = fmaxf(m, b2f(A16[(size_t)node * 128 + d]));
    }
    atomicMax((int*)&gbuf[curg * GDIM + off + d], __float_as_int(m));
}

// ---------------- final: out[G,128] = gbuf[G,640] @ Wa[640,128] + ba

__global__ __launch_bounds__(128) void k_final(const float* __restrict__ gbuf,
                                               const float* __restrict__ Wa,
                                               const float* __restrict__ ba,
                                               float* __restrict__ out) {
    __shared__ float gr[GDIM];
    int g = blockIdx.x, t = threadIdx.x;
    for (int i = t; i < GDIM; i += 128) gr[i] = gbuf[g * GDIM + i];
    __syncthreads();
    float acc = ba[t];
    for (int k = 0; k < GDIM; ++k) acc = fmaf(gr[k], Wa[k * 128 + t], acc);
    out[g * 128 + t] = acc;
}

// ---------------- launch ----------------

extern "C" void kernel_launch(void* const* d_in, const int* in_sizes, int n_in,
                              void* d_out, int out_size, void* d_ws, size_t ws_size,
                              hipStream_t stream) {
    const float* pos    = (const float*)d_in[0];
    const int*   idfeat = (const int*)d_in[1];
    const int*   eidx   = (const int*)d_in[2];
    const int*   batch  = (const int*)d_in[3];
    const float* Wp     = (const float*)d_in[5];
    const float* bp     = (const float*)d_in[6];
    const float* id_emb = (const float*)d_in[7];
    const float* Wn     = (const float*)d_in[8];
    const float* bn     = (const float*)d_in[9];
    const float* convW  = (const float*)d_in[10];
    const float* convb  = (const float*)d_in[11];
    const float* Wa     = (const float*)d_in[12];
    const float* ba     = (const float*)d_in[13];
    float* out = (float*)d_out;

    const int* esrc = eidx;
    const int* edst = eidx + N_EDGES;

    char* w = (char*)d_ws;
    auto alloc = [&](size_t bytes) -> char* {
        char* p = w;
        w += (bytes + 255) & ~(size_t)255;
        return p;
    };
    unsigned short* A16 = (unsigned short*)alloc((size_t)N_NODES * D * 2);
    unsigned short* Bb  = (unsigned short*)alloc((size_t)N_NODES * D * 2);
    float* dinv = (float*)alloc((size_t)N_NODES * 4);
    int*   cnt  = (int*)alloc((size_t)N_NODES * 4);
    int*   offs = (int*)alloc((size_t)(N_NODES + 1) * 4);
    int*   fillp= (int*)alloc((size_t)N_NODES * 4);
    int*   csum = (int*)alloc(64 * 4);
    int*   coff = (int*)alloc(64 * 4);
    int*   csrs = (int*)alloc((size_t)N_EDGES * 4);
    int2*  ebuf = (int2*)alloc((size_t)N_EDGES * 8);
    int*   btail= (int*)alloc(NBUCK * 4);
    float* gbuf = (float*)alloc((size_t)NGRAPH * GDIM * 4);
    float* T    = (float*)alloc((size_t)256 * D * 4);
    unsigned short* Wpack = (unsigned short*)alloc((size_t)5 * 16384 * 2);

    hipMemsetAsync(cnt, 0, (size_t)N_NODES * 4, stream);
    hipMemsetAsync(fillp, 0, (size_t)N_NODES * 4, stream);
    hipMemsetAsync(gbuf, 0, (size_t)NGRAPH * GDIM * 4, stream);

    k_count<<<(N_EDGES + 255) / 256, 256, 0, stream>>>(edst, cnt);
    k_dinv<<<(N_NODES + 255) / 256, 256, 0, stream>>>(cnt, dinv);

    int nchunk = (N_NODES + 1023) / 1024; // 49
    k_scanA<<<nchunk, 256, 0, stream>>>(cnt, offs, csum);
    k_scanB<<<1, 64, 0, stream>>>(csum, coff, nchunk);
    k_scanC<<<(N_NODES + 255) / 256, 256, 0, stream>>>(offs, coff);

    k_btail<<<1, 256, 0, stream>>>(offs, btail);
    k_bucket<<<(N_EDGES + 4095) / 4096, 256, 0, stream>>>(esrc, edst, btail, ebuf);
    k_fill2<<<(N_EDGES + 255) / 256, 256, 0, stream>>>(ebuf, offs, fillp, csrs);

    k_packW<<<(5 * 16384 + 255) / 256, 256, 0, stream>>>(Wn, convW, Wpack);
    k_idT<<<128, 256, 0, stream>>>(id_emb, Wn, T);
    k_encoder<<<(N_NODES + 63) / 64, 256, 0, stream>>>(pos, idfeat, Wp, bp, Wpack, bn, T, A16);

    int segmax_blocks = ((((N_NODES + 31) / 32) * 128) + 255) / 256;
    k_segmax<<<segmax_blocks, 256, 0, stream>>>(A16, gbuf, batch, 0);

    for (int l = 0; l < NLAYER; ++l) {
        k_gemm<<<(N_NODES + 63) / 64, 256, 0, stream>>>(A16, Wpack + (size_t)(l + 1) * 16384, Bb);
        k_gather<<<(N_NODES + 7) / 8, 256, 0, stream>>>(Bb, A16, offs, cnt, csrs, dinv,
                                                        convb + (size_t)l * D);
        k_segmax<<<segmax_blocks, 256, 0, stream>>>(A16, gbuf, batch, (l + 1) * D);
    }

    k_final<<<NGRAPH, 128, 0, stream>>>(gbuf, Wa, ba, out);
}

// Round 8
// 354.300 us; speedup vs baseline: 1.2252x; 1.2252x over previous
//
#include <hip/hip_runtime.h>

#define N_NODES 50000
#define N_EDGES 800000
#define D 128
#define NLAYER 4
#define NGRAPH 128
#define GDIM (5 * D) // 640
#define NBUCK 196    // dst>>8 buckets

typedef __attribute__((ext_vector_type(8))) short bf16x8;
typedef __attribute__((ext_vector_type(4))) float f32x4;

__device__ __forceinline__ float b2f(unsigned short u) {
    return __uint_as_float(((unsigned)u) << 16);
}
__device__ __forceinline__ unsigned short f2b(float f) {
    unsigned u = __float_as_uint(f);
    unsigned r = (u + 0x7fffu + ((u >> 16) & 1u)) >> 16; // round-to-nearest-even
    return (unsigned short)r;
}

// ---------------- CSR build ----------------

__global__ void k_count(const int* __restrict__ edst, int* __restrict__ cnt) {
    int e = blockIdx.x * 256 + threadIdx.x;
    if (e < N_EDGES) atomicAdd(&cnt[edst[e]], 1);
}

__global__ void k_scanA(const int* __restrict__ cnt, int* __restrict__ offs,
                        int* __restrict__ chunkSum) {
    __shared__ int lds[256];
    int tid = threadIdx.x;
    int base = blockIdx.x * 1024 + tid * 4;
    int v[4];
    int s = 0;
#pragma unroll
    for (int j = 0; j < 4; ++j) {
        int idx = base + j;
        v[j] = (idx < N_NODES) ? cnt[idx] : 0;
        s += v[j];
    }
    lds[tid] = s;
    __syncthreads();
    int t = s;
    for (int off = 1; off < 256; off <<= 1) {
        int add = (tid >= off) ? lds[tid - off] : 0;
        __syncthreads();
        t += add;
        lds[tid] = t;
        __syncthreads();
    }
    int run = t - s;
#pragma unroll
    for (int j = 0; j < 4; ++j) {
        int idx = base + j;
        if (idx < N_NODES) offs[idx] = run;
        run += v[j];
    }
    if (tid == 255) chunkSum[blockIdx.x] = t;
}

__global__ void k_scanB(const int* __restrict__ chunkSum, int* __restrict__ chunkOff,
                        int nc) {
    __shared__ int lds[64];
    int tid = threadIdx.x;
    int v = (tid < nc) ? chunkSum[tid] : 0;
    lds[tid] = v;
    __syncthreads();
    int t = v;
    for (int off = 1; off < 64; off <<= 1) {
        int add = (tid >= off) ? lds[tid - off] : 0;
        __syncthreads();
        t += add;
        lds[tid] = t;
        __syncthreads();
    }
    if (tid < nc) chunkOff[tid] = t - v;
}

// finalize offs; also produce dinv, btail (mutable), bstart (const)
__global__ void k_scanC(int* __restrict__ offs, const int* __restrict__ chunkOff,
                        const int* __restrict__ cnt, float* __restrict__ dinv,
                        int* __restrict__ btail, int* __restrict__ bstart) {
    int i = blockIdx.x * 256 + threadIdx.x;
    if (i < N_NODES) {
        int v = offs[i] + chunkOff[i >> 10];
        offs[i] = v;
        dinv[i] = 1.f / sqrtf((float)(cnt[i] + 1)); // +1 self-loop
        if ((i & 255) == 0) { btail[i >> 8] = v; bstart[i >> 8] = v; }
        if (i == 0) bstart[NBUCK] = N_EDGES;
    }
}

// Pass A: bucket edges by dst>>8 into bucket-major ebuf (packed src|((dst&255)<<16))
__global__ __launch_bounds__(256) void k_bucket(
    const int* __restrict__ esrc, const int* __restrict__ edst,
    int* __restrict__ btail, int* __restrict__ ebuf) {
    __shared__ int hcnt[NBUCK];
    __shared__ int hbase[NBUCK];
    int t = threadIdx.x;
    for (int i = t; i < NBUCK; i += 256) hcnt[i] = 0;
    __syncthreads();
    int e0 = blockIdx.x * 2048 + t;
    int d[8], s[8];
#pragma unroll
    for (int i = 0; i < 8; ++i) {
        int e = e0 + i * 256;
        if (e < N_EDGES) {
            d[i] = edst[e];
            s[i] = esrc[e];
            atomicAdd(&hcnt[d[i] >> 8], 1);
        } else {
            d[i] = -1;
        }
    }
    __syncthreads();
    for (int i = t; i < NBUCK; i += 256) {
        int c = hcnt[i];
        hbase[i] = (c > 0) ? atomicAdd(&btail[i], c) : 0;
        hcnt[i] = 0;
    }
    __syncthreads();
#pragma unroll
    for (int i = 0; i < 8; ++i) {
        if (d[i] >= 0) {
            int b = d[i] >> 8;
            int p = atomicAdd(&hcnt[b], 1);
            ebuf[hbase[b] + p] = (s[i] & 0xffff) | ((d[i] & 255) << 16);
        }
    }
}

// Pass B: one block per bucket; LDS per-dst counters; writes confined to the
// bucket's CSR window (single writer -> L2-local, no line ping-pong).
__global__ __launch_bounds__(256) void k_fillB(
    const int* __restrict__ ebuf, const int* __restrict__ bstart,
    const int* __restrict__ offs, int* __restrict__ csrs) {
    __shared__ int loffs[256];
    __shared__ int lcnt[256];
    int b = blockIdx.x, t = threadIdx.x;
    int nbase = b << 8;
    if (nbase + t < N_NODES) loffs[t] = offs[nbase + t];
    lcnt[t] = 0;
    __syncthreads();
    int s0 = bstart[b], s1 = bstart[b + 1];
    for (int i = s0 + t; i < s1; i += 256) {
        int pk = ebuf[i];
        int ld = (pk >> 16) & 255;
        int src = pk & 0xffff;
        int p = atomicAdd(&lcnt[ld], 1);
        csrs[loffs[ld] + p] = src;
    }
}

// ---------------- prep: Wpack (blocks 0..319) + T = relu(id_emb)@Wn_bot (320..447)

__global__ __launch_bounds__(256) void k_prep(
    const float* __restrict__ Wn, const float* __restrict__ convW,
    unsigned short* __restrict__ Wpack,
    const float* __restrict__ id_emb, float* __restrict__ T) {
    int blk = blockIdx.x;
    if (blk < 320) {
        int tid = blk * 256 + threadIdx.x;
        int m = tid >> 14;
        int rem = tid & 16383;
        int ct = rem >> 11, kc = (rem >> 9) & 3, l = (rem >> 3) & 63, j = rem & 7;
        int k = kc * 32 + ((l >> 4) * 8) + j;
        int n = ct * 16 + (l & 15);
        const float* src = (m == 0) ? Wn : (convW + (size_t)(m - 1) * 16384);
        Wpack[tid] = f2b(src[k * 128 + n]);
    } else {
        int t = threadIdx.x;
        int d = t & 127;
        int r = (blk - 320) * 2 + (t >> 7);
        float acc = 0.f;
        for (int k = 0; k < 128; ++k)
            acc = fmaf(fmaxf(id_emb[r * 128 + k], 0.f), Wn[(128 + k) * 128 + d], acc);
        T[r * 128 + d] = acc;
    }
}

// ---------------- MFMA encoder: A16 = bf16(relu(posrelu @ Wn_top + T[id] + bn)) ----

__global__ __launch_bounds__(256) void k_encoder(
    const float* __restrict__ pos, const int* __restrict__ idfeat,
    const float* __restrict__ Wp, const float* __restrict__ bp,
    const unsigned short* __restrict__ WpackE, const float* __restrict__ bn,
    const float* __restrict__ T, unsigned short* __restrict__ A16) {
    __shared__ unsigned short feat[64 * 128]; // 16KB, swizzled
    __shared__ float posl[192];
    int t = threadIdx.x;
    int base = blockIdx.x * 64;
    int avail = N_NODES - base;
    if (t < 192) {
        int idx = base * 3 + t;
        posl[t] = (idx < N_NODES * 3) ? pos[idx] : 0.f;
    }
    __syncthreads();
#pragma unroll
    for (int i = 0; i < 4; ++i) {
        int gid = t + i * 256;
        int row = gid >> 4, kg = gid & 15;
        unsigned short u[8];
        if (row < avail) {
            float p0 = posl[row * 3], p1 = posl[row * 3 + 1], p2 = posl[row * 3 + 2];
#pragma unroll
            for (int j = 0; j < 8; ++j) {
                int d = kg * 8 + j;
                float v = fmaf(p0, Wp[d], fmaf(p1, Wp[128 + d], fmaf(p2, Wp[256 + d], bp[d])));
                u[j] = f2b(fmaxf(v, 0.f));
            }
        } else {
#pragma unroll
            for (int j = 0; j < 8; ++j) u[j] = 0;
        }
        char* dst = (char*)feat + row * 256 + ((kg * 16) ^ ((row & 7) << 4));
        *(uint4*)dst = *(uint4*)u;
    }
    __syncthreads();
    int wid = t >> 6, l = t & 63;
    int r0 = wid * 16;
    f32x4 acc[8];
#pragma unroll
    for (int ct = 0; ct < 8; ++ct) acc[ct] = (f32x4){0.f, 0.f, 0.f, 0.f};
    const bf16x8* wp = (const bf16x8*)WpackE;
#pragma unroll
    for (int kc = 0; kc < 4; ++kc) {
        int row = r0 + (l & 15);
        const char* ap = (const char*)feat + row * 256 +
                         ((kc * 64 + ((l >> 4) * 16)) ^ ((row & 7) << 4));
        bf16x8 afrag = *(const bf16x8*)ap;
#pragma unroll
        for (int ct = 0; ct < 8; ++ct) {
            bf16x8 bfrag = wp[(ct * 4 + kc) * 64 + l];
            acc[ct] = __builtin_amdgcn_mfma_f32_16x16x32_bf16(afrag, bfrag, acc[ct], 0, 0, 0);
        }
    }
    int subrow = (l >> 4) * 4, col0 = l & 15;
    int ids[4];
#pragma unroll
    for (int i = 0; i < 4; ++i) {
        int node = base + r0 + subrow + i;
        ids[i] = (node < N_NODES) ? idfeat[node] : 0;
    }
#pragma unroll
    for (int ct = 0; ct < 8; ++ct) {
        int col = ct * 16 + col0;
        float bcol = bn[col];
#pragma unroll
        for (int i = 0; i < 4; ++i) {
            int node = base + r0 + subrow + i;
            if (node < N_NODES) {
                float v = acc[ct][i] + bcol + T[ids[i] * 128 + col];
                A16[(size_t)node * 128 + col] = f2b(fmaxf(v, 0.f));
            }
        }
    }
}

// ---------------- MFMA GEMM: Bb[N,128](bf16) = A16[N,128](bf16) @ W ----------

__global__ __launch_bounds__(256) void k_gemm(
    const unsigned short* __restrict__ H16, const unsigned short* __restrict__ WpackL,
    unsigned short* __restrict__ Bb) {
    __shared__ unsigned short feat[64 * 128]; // 16KB, swizzled
    int t = threadIdx.x;
    int base = blockIdx.x * 64;
    int avail = N_NODES - base;
#pragma unroll
    for (int i = 0; i < 4; ++i) {
        int gid = t + i * 256;
        int row = gid >> 4, kg = gid & 15;
        uint4 v = make_uint4(0, 0, 0, 0);
        if (row < avail)
            v = *(const uint4*)&H16[(size_t)(base + row) * 128 + kg * 8];
        char* dst = (char*)feat + row * 256 + ((kg * 16) ^ ((row & 7) << 4));
        *(uint4*)dst = v;
    }
    __syncthreads();
    int wid = t >> 6, l = t & 63;
    int r0 = wid * 16;
    f32x4 acc[8];
#pragma unroll
    for (int ct = 0; ct < 8; ++ct) acc[ct] = (f32x4){0.f, 0.f, 0.f, 0.f};
    const bf16x8* wp = (const bf16x8*)WpackL;
#pragma unroll
    for (int kc = 0; kc < 4; ++kc) {
        int row = r0 + (l & 15);
        const char* ap = (const char*)feat + row * 256 +
                         ((kc * 64 + ((l >> 4) * 16)) ^ ((row & 7) << 4));
        bf16x8 afrag = *(const bf16x8*)ap;
#pragma unroll
        for (int ct = 0; ct < 8; ++ct) {
            bf16x8 bfrag = wp[(ct * 4 + kc) * 64 + l];
            acc[ct] = __builtin_amdgcn_mfma_f32_16x16x32_bf16(afrag, bfrag, acc[ct], 0, 0, 0);
        }
    }
    int subrow = (l >> 4) * 4, col0 = l & 15;
#pragma unroll
    for (int ct = 0; ct < 8; ++ct) {
#pragma unroll
        for (int i = 0; i < 4; ++i) {
            int node = base + r0 + subrow + i;
            if (node < N_NODES)
                Bb[(size_t)node * 128 + ct * 16 + col0] = f2b(acc[ct][i]);
        }
    }
}

// ---------------- GCN aggregate + fused segment-max ----------------
// A16[i] = bf16(relu(sum_e w_e*B[src] + dinv_i^2*B[i] + bias))
// Per block: 8 nodes; LDS reduce fp32 acc across nodes sharing batch id, then
// one atomicMax per column per (block,graph).

__global__ __launch_bounds__(256) void k_gather(
    const unsigned short* __restrict__ B, unsigned short* __restrict__ A16,
    const int* __restrict__ offs, const int* __restrict__ cnt,
    const int* __restrict__ csrs, const float* __restrict__ dinv,
    const float* __restrict__ bias, const int* __restrict__ batch,
    float* __restrict__ gbuf, int goff) {
    __shared__ float smx[8][128];
    __shared__ int bb[8];
    int tid = threadIdx.x;
    int lane = tid & 63;
    int sub = lane >> 5;
    int l = lane & 31;
    int nidx = (tid >> 6) * 2 + sub; // 0..7
    int node = blockIdx.x * 8 + nidx; // N_NODES % 8 == 0 -> always valid
    if (tid < 8) bb[tid] = batch[blockIdx.x * 8 + tid];
    int start = offs[node];
    int c = cnt[node];
    float di = dinv[node];
    float sw = di * di;
    const ushort4* B4 = (const ushort4*)B; // 32 ushort4 per row
    ushort4 sv = B4[(size_t)node * 32 + l];
    float4 acc;
    acc.x = sw * b2f(sv.x);
    acc.y = sw * b2f(sv.y);
    acc.z = sw * b2f(sv.z);
    acc.w = sw * b2f(sv.w);
#pragma unroll 2
    for (int j = 0; j < c; ++j) {
        int s = csrs[start + j];
        float w = di * dinv[s];
        ushort4 v = B4[(size_t)s * 32 + l];
        acc.x = fmaf(w, b2f(v.x), acc.x);
        acc.y = fmaf(w, b2f(v.y), acc.y);
        acc.z = fmaf(w, b2f(v.z), acc.z);
        acc.w = fmaf(w, b2f(v.w), acc.w);
    }
    float4 bv = ((const float4*)bias)[l];
    acc.x = fmaxf(acc.x + bv.x, 0.f);
    acc.y = fmaxf(acc.y + bv.y, 0.f);
    acc.z = fmaxf(acc.z + bv.z, 0.f);
    acc.w = fmaxf(acc.w + bv.w, 0.f);
    ushort4 o;
    o.x = f2b(acc.x); o.y = f2b(acc.y); o.z = f2b(acc.z); o.w = f2b(acc.w);
    ((ushort4*)(A16 + (size_t)node * 128))[l] = o;
    *(float4*)&smx[nidx][l * 4] = acc;
    __syncthreads();
    if (tid < 128) {
        float* gm = gbuf + goff;
        if (bb[0] == bb[7]) {
            float m = smx[0][tid];
#pragma unroll
            for (int j = 1; j < 8; ++j) m = fmaxf(m, smx[j][tid]);
            atomicMax((int*)&gm[bb[0] * GDIM + tid], __float_as_int(m));
        } else {
            int j = 0;
            while (j < 8) {
                int g = bb[j];
                float m = smx[j][tid];
                int k = j + 1;
                while (k < 8 && bb[k] == g) { m = fmaxf(m, smx[k][tid]); ++k; }
                atomicMax((int*)&gm[g * GDIM + tid], __float_as_int(m));
                j = k;
            }
        }
    }
}

// ---------------- segment max over bf16 A (layer 0 only) ----------------

__global__ void k_segmax(const unsigned short* __restrict__ A16,
                         float* __restrict__ gbuf,
                         const int* __restrict__ batch, int off) {
    int gid = blockIdx.x * blockDim.x + threadIdx.x;
    int d = gid & 127;
    int chunk = gid >> 7;
    int n0 = chunk * 32;
    if (n0 >= N_NODES) return;
    int nend = n0 + 32;
    if (nend > N_NODES) nend = N_NODES;
    float m = 0.f;
    int curg = batch[n0];
    for (int node = n0; node < nend; ++node) {
        int g = batch[node];
        if (g != curg) {
            atomicMax((int*)&gbuf[curg * GDIM + off + d], __float_as_int(m));
            curg = g;
            m = 0.f;
        }
        m = fmaxf(m, b2f(A16[(size_t)node * 128 + d]));
    }
    atomicMax((int*)&gbuf[curg * GDIM + off + d], __float_as_int(m));
}

// ---------------- final: out[G,128] = gbuf[G,640] @ Wa[640,128] + ba

__global__ __launch_bounds__(128) void k_final(const float* __restrict__ gbuf,
                                               const float* __restrict__ Wa,
                                               const float* __restrict__ ba,
                                               float* __restrict__ out) {
    __shared__ float gr[GDIM];
    int g = blockIdx.x, t = threadIdx.x;
    for (int i = t; i < GDIM; i += 128) gr[i] = gbuf[g * GDIM + i];
    __syncthreads();
    float acc = ba[t];
    for (int k = 0; k < GDIM; ++k) acc = fmaf(gr[k], Wa[k * 128 + t], acc);
    out[g * 128 + t] = acc;
}

// ---------------- launch ----------------

extern "C" void kernel_launch(void* const* d_in, const int* in_sizes, int n_in,
                              void* d_out, int out_size, void* d_ws, size_t ws_size,
                              hipStream_t stream) {
    const float* pos    = (const float*)d_in[0];
    const int*   idfeat = (const int*)d_in[1];
    const int*   eidx   = (const int*)d_in[2];
    const int*   batch  = (const int*)d_in[3];
    const float* Wp     = (const float*)d_in[5];
    const float* bp     = (const float*)d_in[6];
    const float* id_emb = (const float*)d_in[7];
    const float* Wn     = (const float*)d_in[8];
    const float* bn     = (const float*)d_in[9];
    const float* convW  = (const float*)d_in[10];
    const float* convb  = (const float*)d_in[11];
    const float* Wa     = (const float*)d_in[12];
    const float* ba     = (const float*)d_in[13];
    float* out = (float*)d_out;

    const int* esrc = eidx;
    const int* edst = eidx + N_EDGES;

    char* w = (char*)d_ws;
    auto alloc = [&](size_t bytes) -> char* {
        char* p = w;
        w += (bytes + 255) & ~(size_t)255;
        return p;
    };
    // cnt and gbuf adjacent -> single memset clears both
    int*   cnt  = (int*)alloc((size_t)N_NODES * 4);          // 200192 padded
    float* gbuf = (float*)alloc((size_t)NGRAPH * GDIM * 4);  // 327680
    size_t zbytes = ((size_t)N_NODES * 4 + 255 & ~(size_t)255) + (size_t)NGRAPH * GDIM * 4;
    unsigned short* A16 = (unsigned short*)alloc((size_t)N_NODES * D * 2);
    unsigned short* Bb  = (unsigned short*)alloc((size_t)N_NODES * D * 2);
    float* dinv = (float*)alloc((size_t)N_NODES * 4);
    int*   offs = (int*)alloc((size_t)(N_NODES + 1) * 4);
    int*   csum = (int*)alloc(64 * 4);
    int*   coff = (int*)alloc(64 * 4);
    int*   csrs = (int*)alloc((size_t)N_EDGES * 4);
    int*   ebuf = (int*)alloc((size_t)N_EDGES * 4);
    int*   btail= (int*)alloc((NBUCK + 1) * 4);
    int*   bstart=(int*)alloc((NBUCK + 1) * 4);
    float* T    = (float*)alloc((size_t)256 * D * 4);
    unsigned short* Wpack = (unsigned short*)alloc((size_t)5 * 16384 * 2);

    hipMemsetAsync(cnt, 0, zbytes, stream);

    k_count<<<(N_EDGES + 255) / 256, 256, 0, stream>>>(edst, cnt);

    int nchunk = (N_NODES + 1023) / 1024; // 49
    k_scanA<<<nchunk, 256, 0, stream>>>(cnt, offs, csum);
    k_scanB<<<1, 64, 0, stream>>>(csum, coff, nchunk);
    k_scanC<<<(N_NODES + 255) / 256, 256, 0, stream>>>(offs, coff, cnt, dinv, btail, bstart);

    k_bucket<<<(N_EDGES + 2047) / 2048, 256, 0, stream>>>(esrc, edst, btail, ebuf);
    k_fillB<<<NBUCK, 256, 0, stream>>>(ebuf, bstart, offs, csrs);

    k_prep<<<448, 256, 0, stream>>>(Wn, convW, Wpack, id_emb, T);
    k_encoder<<<(N_NODES + 63) / 64, 256, 0, stream>>>(pos, idfeat, Wp, bp, Wpack, bn, T, A16);

    int segmax_blocks = ((((N_NODES + 31) / 32) * 128) + 255) / 256;
    k_segmax<<<segmax_blocks, 256, 0, stream>>>(A16, gbuf, batch, 0);

    for (int l = 0; l < NLAYER; ++l) {
        k_gemm<<<(N_NODES + 63) / 64, 256, 0, stream>>>(A16, Wpack + (size_t)(l + 1) * 16384, Bb);
        k_gather<<<N_NODES / 8, 256, 0, stream>>>(Bb, A16, offs, cnt, csrs, dinv,
                                                  convb + (size_t)l * D, batch, gbuf, (l + 1) * D);
    }

    k_final<<<NGRAPH, 128, 0, stream>>>(gbuf, Wa, ba, out);
}

// Round 9
// 295.482 us; speedup vs baseline: 1.4691x; 1.1991x over previous
//
#include <hip/hip_runtime.h>

#define N_NODES 50000
#define N_EDGES 800000
#define D 128
#define NLAYER 4
#define NGRAPH 128
#define GDIM (5 * D) // 640
#define NBUCK 196    // dst>>8 buckets

typedef __attribute__((ext_vector_type(8))) short bf16x8;
typedef __attribute__((ext_vector_type(4))) float f32x4;

__device__ __forceinline__ float b2f(unsigned short u) {
    return __uint_as_float(((unsigned)u) << 16);
}
__device__ __forceinline__ unsigned short f2b(float f) {
    unsigned u = __float_as_uint(f);
    unsigned r = (u + 0x7fffu + ((u >> 16) & 1u)) >> 16; // round-to-nearest-even
    return (unsigned short)r;
}

// ---------------- CSR build ----------------

__global__ void k_count(const int* __restrict__ edst, int* __restrict__ cnt) {
    int e = blockIdx.x * 256 + threadIdx.x;
    if (e < N_EDGES) atomicAdd(&cnt[edst[e]], 1);
}

__global__ void k_scanA(const int* __restrict__ cnt, int* __restrict__ offs,
                        int* __restrict__ chunkSum) {
    __shared__ int lds[256];
    int tid = threadIdx.x;
    int base = blockIdx.x * 1024 + tid * 4;
    int v[4];
    int s = 0;
#pragma unroll
    for (int j = 0; j < 4; ++j) {
        int idx = base + j;
        v[j] = (idx < N_NODES) ? cnt[idx] : 0;
        s += v[j];
    }
    lds[tid] = s;
    __syncthreads();
    int t = s;
    for (int off = 1; off < 256; off <<= 1) {
        int add = (tid >= off) ? lds[tid - off] : 0;
        __syncthreads();
        t += add;
        lds[tid] = t;
        __syncthreads();
    }
    int run = t - s;
#pragma unroll
    for (int j = 0; j < 4; ++j) {
        int idx = base + j;
        if (idx < N_NODES) offs[idx] = run;
        run += v[j];
    }
    if (tid == 255) chunkSum[blockIdx.x] = t;
}

__global__ void k_scanB(const int* __restrict__ chunkSum, int* __restrict__ chunkOff,
                        int nc) {
    __shared__ int lds[64];
    int tid = threadIdx.x;
    int v = (tid < nc) ? chunkSum[tid] : 0;
    lds[tid] = v;
    __syncthreads();
    int t = v;
    for (int off = 1; off < 64; off <<= 1) {
        int add = (tid >= off) ? lds[tid - off] : 0;
        __syncthreads();
        t += add;
        lds[tid] = t;
        __syncthreads();
    }
    if (tid < nc) chunkOff[tid] = t - v;
}

// finalize offs; also produce dinv, btail (mutable), bstart (const)
__global__ void k_scanC(int* __restrict__ offs, const int* __restrict__ chunkOff,
                        const int* __restrict__ cnt, float* __restrict__ dinv,
                        int* __restrict__ btail, int* __restrict__ bstart) {
    int i = blockIdx.x * 256 + threadIdx.x;
    if (i < N_NODES) {
        int v = offs[i] + chunkOff[i >> 10];
        offs[i] = v;
        dinv[i] = 1.f / sqrtf((float)(cnt[i] + 1)); // +1 self-loop
        if ((i & 255) == 0) { btail[i >> 8] = v; bstart[i >> 8] = v; }
        if (i == 0) bstart[NBUCK] = N_EDGES;
    }
}

// Pass A: bucket edges by dst>>8 into bucket-major ebuf (packed src|((dst&255)<<16))
__global__ __launch_bounds__(256) void k_bucket(
    const int* __restrict__ esrc, const int* __restrict__ edst,
    int* __restrict__ btail, int* __restrict__ ebuf) {
    __shared__ int hcnt[NBUCK];
    __shared__ int hbase[NBUCK];
    int t = threadIdx.x;
    for (int i = t; i < NBUCK; i += 256) hcnt[i] = 0;
    __syncthreads();
    int e0 = blockIdx.x * 2048 + t;
    int d[8], s[8];
#pragma unroll
    for (int i = 0; i < 8; ++i) {
        int e = e0 + i * 256;
        if (e < N_EDGES) {
            d[i] = edst[e];
            s[i] = esrc[e];
            atomicAdd(&hcnt[d[i] >> 8], 1);
        } else {
            d[i] = -1;
        }
    }
    __syncthreads();
    for (int i = t; i < NBUCK; i += 256) {
        int c = hcnt[i];
        hbase[i] = (c > 0) ? atomicAdd(&btail[i], c) : 0;
        hcnt[i] = 0;
    }
    __syncthreads();
#pragma unroll
    for (int i = 0; i < 8; ++i) {
        if (d[i] >= 0) {
            int b = d[i] >> 8;
            int p = atomicAdd(&hcnt[b], 1);
            ebuf[hbase[b] + p] = (s[i] & 0xffff) | ((d[i] & 255) << 16);
        }
    }
}

// Pass B: one block per bucket; LDS per-dst counters; writes confined to the
// bucket's CSR window (single writer -> L2-local).
__global__ __launch_bounds__(256) void k_fillB(
    const int* __restrict__ ebuf, const int* __restrict__ bstart,
    const int* __restrict__ offs, int* __restrict__ csrs) {
    __shared__ int loffs[256];
    __shared__ int lcnt[256];
    int b = blockIdx.x, t = threadIdx.x;
    int nbase = b << 8;
    if (nbase + t < N_NODES) loffs[t] = offs[nbase + t];
    lcnt[t] = 0;
    __syncthreads();
    int s0 = bstart[b], s1 = bstart[b + 1];
    for (int i = s0 + t; i < s1; i += 256) {
        int pk = ebuf[i];
        int ld = (pk >> 16) & 255;
        int src = pk & 0xffff;
        int p = atomicAdd(&lcnt[ld], 1);
        csrs[loffs[ld] + p] = src;
    }
}

// ---------------- prep: Wpack (blocks 0..319) + T = relu(id_emb)@Wn_bot (320..447)

__global__ __launch_bounds__(256) void k_prep(
    const float* __restrict__ Wn, const float* __restrict__ convW,
    unsigned short* __restrict__ Wpack,
    const float* __restrict__ id_emb, float* __restrict__ T) {
    int blk = blockIdx.x;
    if (blk < 320) {
        int tid = blk * 256 + threadIdx.x;
        int m = tid >> 14;
        int rem = tid & 16383;
        int ct = rem >> 11, kc = (rem >> 9) & 3, l = (rem >> 3) & 63, j = rem & 7;
        int k = kc * 32 + ((l >> 4) * 8) + j;
        int n = ct * 16 + (l & 15);
        const float* src = (m == 0) ? Wn : (convW + (size_t)(m - 1) * 16384);
        Wpack[tid] = f2b(src[k * 128 + n]);
    } else {
        int t = threadIdx.x;
        int d = t & 127;
        int r = (blk - 320) * 2 + (t >> 7);
        float acc = 0.f;
        for (int k = 0; k < 128; ++k)
            acc = fmaf(fmaxf(id_emb[r * 128 + k], 0.f), Wn[(128 + k) * 128 + d], acc);
        T[r * 128 + d] = acc;
    }
}

// ---------------- MFMA encoder + fused segmax (layer 0) ----------------

__global__ __launch_bounds__(256) void k_encoder(
    const float* __restrict__ pos, const int* __restrict__ idfeat,
    const float* __restrict__ Wp, const float* __restrict__ bp,
    const unsigned short* __restrict__ WpackE, const float* __restrict__ bn,
    const float* __restrict__ T, unsigned short* __restrict__ A16,
    const int* __restrict__ batch, float* __restrict__ gbuf) {
    __shared__ unsigned short feat[64 * 128]; // 16KB, swizzled; reused as smx
    __shared__ float posl[192];
    __shared__ int bbat[64];
    int t = threadIdx.x;
    int base = blockIdx.x * 64;
    int avail = N_NODES - base;
    if (t < 192) {
        int idx = base * 3 + t;
        posl[t] = (idx < N_NODES * 3) ? pos[idx] : 0.f;
    }
    if (t < 64) bbat[t] = (base + t < N_NODES) ? batch[base + t] : -1;
    __syncthreads();
#pragma unroll
    for (int i = 0; i < 4; ++i) {
        int gid = t + i * 256;
        int row = gid >> 4, kg = gid & 15;
        unsigned short u[8];
        if (row < avail) {
            float p0 = posl[row * 3], p1 = posl[row * 3 + 1], p2 = posl[row * 3 + 2];
#pragma unroll
            for (int j = 0; j < 8; ++j) {
                int d = kg * 8 + j;
                float v = fmaf(p0, Wp[d], fmaf(p1, Wp[128 + d], fmaf(p2, Wp[256 + d], bp[d])));
                u[j] = f2b(fmaxf(v, 0.f));
            }
        } else {
#pragma unroll
            for (int j = 0; j < 8; ++j) u[j] = 0;
        }
        char* dst = (char*)feat + row * 256 + ((kg * 16) ^ ((row & 7) << 4));
        *(uint4*)dst = *(uint4*)u;
    }
    __syncthreads();
    int wid = t >> 6, l = t & 63;
    int r0 = wid * 16;
    f32x4 acc[8];
#pragma unroll
    for (int ct = 0; ct < 8; ++ct) acc[ct] = (f32x4){0.f, 0.f, 0.f, 0.f};
    const bf16x8* wp = (const bf16x8*)WpackE;
#pragma unroll
    for (int kc = 0; kc < 4; ++kc) {
        int row = r0 + (l & 15);
        const char* ap = (const char*)feat + row * 256 +
                         ((kc * 64 + ((l >> 4) * 16)) ^ ((row & 7) << 4));
        bf16x8 afrag = *(const bf16x8*)ap;
#pragma unroll
        for (int ct = 0; ct < 8; ++ct) {
            bf16x8 bfrag = wp[(ct * 4 + kc) * 64 + l];
            acc[ct] = __builtin_amdgcn_mfma_f32_16x16x32_bf16(afrag, bfrag, acc[ct], 0, 0, 0);
        }
    }
    int subrow = (l >> 4) * 4, col0 = l & 15;
    int ids[4];
#pragma unroll
    for (int i = 0; i < 4; ++i) {
        int node = base + r0 + subrow + i;
        ids[i] = (node < N_NODES) ? idfeat[node] : 0;
    }
    __syncthreads(); // all MFMA feat reads done; reuse feat as bf16 smx
#pragma unroll
    for (int ct = 0; ct < 8; ++ct) {
        int col = ct * 16 + col0;
        float bcol = bn[col];
#pragma unroll
        for (int i = 0; i < 4; ++i) {
            int node = base + r0 + subrow + i;
            unsigned short ob = 0;
            if (node < N_NODES) {
                float v = acc[ct][i] + bcol + T[ids[i] * 128 + col];
                ob = f2b(fmaxf(v, 0.f));
                A16[(size_t)node * 128 + col] = ob;
            }
            feat[(r0 + subrow + i) * 128 + col] = ob;
        }
    }
    __syncthreads();
    if (t < 128) {
        int j = 0;
        while (j < 64) {
            int g = bbat[j];
            float m = b2f(feat[j * 128 + t]);
            int k = j + 1;
            while (k < 64 && bbat[k] == g) { m = fmaxf(m, b2f(feat[k * 128 + t])); ++k; }
            if (g >= 0) atomicMax((int*)&gbuf[g * GDIM + t], __float_as_int(m));
            j = k;
        }
    }
}

// ---------------- fused GCN layer: aggregate(h) -> @W -> +b -> relu -> segmax ----
// out[i] = relu((sum_e norm_e h[src] + dinv_i^2 h[i]) @ W + b)   [GCN linearity]
// Block: 512 threads (8 waves), 16 nodes. Phase1: wave w aggregates nodes 2w,2w+1
// into swizzled bf16 LDS tile. Phase2: wave w MFMAs cols [16w,16w+16). Phase3:
// bias+relu+store + fused segmax.

__global__ __launch_bounds__(512) void k_layer(
    const unsigned short* __restrict__ Hin, unsigned short* __restrict__ Hout,
    const unsigned short* __restrict__ WpackL,
    const int* __restrict__ offs, const int* __restrict__ cnt,
    const int* __restrict__ csrs, const float* __restrict__ dinv,
    const float* __restrict__ bias, const int* __restrict__ batch,
    float* __restrict__ gbuf, int goff) {
    __shared__ unsigned short hagg[16 * 128]; // 4KB swizzled bf16
    __shared__ float smx[16][132];            // padded, ~8.4KB
    __shared__ int bb[16];
    int tid = threadIdx.x;
    int wave = tid >> 6, lane = tid & 63;
    int sub = lane >> 5, l = lane & 31;
    int row = wave * 2 + sub;                 // 0..15
    int nbase = blockIdx.x * 16;              // 50000 % 16 == 0
    int node = nbase + row;
    if (tid < 16) bb[tid] = batch[nbase + tid];

    // ---- phase 1: aggregate in h-space (fp32 acc over bf16 msgs)
    int start = offs[node];
    int c = cnt[node];
    float di = dinv[node];
    float sw = di * di;
    const ushort4* B4 = (const ushort4*)Hin;
    ushort4 sv = B4[(size_t)node * 32 + l];
    float4 acc;
    acc.x = sw * b2f(sv.x);
    acc.y = sw * b2f(sv.y);
    acc.z = sw * b2f(sv.z);
    acc.w = sw * b2f(sv.w);
    int j = 0;
    for (; j + 4 <= c; j += 4) {
        int s0 = csrs[start + j], s1 = csrs[start + j + 1];
        int s2 = csrs[start + j + 2], s3 = csrs[start + j + 3];
        ushort4 v0 = B4[(size_t)s0 * 32 + l];
        ushort4 v1 = B4[(size_t)s1 * 32 + l];
        ushort4 v2 = B4[(size_t)s2 * 32 + l];
        ushort4 v3 = B4[(size_t)s3 * 32 + l];
        float w0 = di * dinv[s0], w1 = di * dinv[s1];
        float w2 = di * dinv[s2], w3 = di * dinv[s3];
        acc.x = fmaf(w0, b2f(v0.x), acc.x); acc.y = fmaf(w0, b2f(v0.y), acc.y);
        acc.z = fmaf(w0, b2f(v0.z), acc.z); acc.w = fmaf(w0, b2f(v0.w), acc.w);
        acc.x = fmaf(w1, b2f(v1.x), acc.x); acc.y = fmaf(w1, b2f(v1.y), acc.y);
        acc.z = fmaf(w1, b2f(v1.z), acc.z); acc.w = fmaf(w1, b2f(v1.w), acc.w);
        acc.x = fmaf(w2, b2f(v2.x), acc.x); acc.y = fmaf(w2, b2f(v2.y), acc.y);
        acc.z = fmaf(w2, b2f(v2.z), acc.z); acc.w = fmaf(w2, b2f(v2.w), acc.w);
        acc.x = fmaf(w3, b2f(v3.x), acc.x); acc.y = fmaf(w3, b2f(v3.y), acc.y);
        acc.z = fmaf(w3, b2f(v3.z), acc.z); acc.w = fmaf(w3, b2f(v3.w), acc.w);
    }
    for (; j < c; ++j) {
        int s = csrs[start + j];
        float w = di * dinv[s];
        ushort4 v = B4[(size_t)s * 32 + l];
        acc.x = fmaf(w, b2f(v.x), acc.x);
        acc.y = fmaf(w, b2f(v.y), acc.y);
        acc.z = fmaf(w, b2f(v.z), acc.z);
        acc.w = fmaf(w, b2f(v.w), acc.w);
    }
    {
        unsigned short u[4] = {f2b(acc.x), f2b(acc.y), f2b(acc.z), f2b(acc.w)};
        char* dst = (char*)hagg + row * 256 + ((((l >> 1) * 16) ^ ((row & 7) << 4)) + (l & 1) * 8);
        *(uint2*)dst = *(uint2*)u;
    }
    __syncthreads();

    // ---- phase 2: MFMA 16x128 @ 128x128, wave -> col tile
    f32x4 oacc = (f32x4){0.f, 0.f, 0.f, 0.f};
    const bf16x8* wp = (const bf16x8*)WpackL;
#pragma unroll
    for (int kc = 0; kc < 4; ++kc) {
        int arow = lane & 15;
        const char* ap = (const char*)hagg + arow * 256 +
                         ((kc * 64 + ((lane >> 4) * 16)) ^ ((arow & 7) << 4));
        bf16x8 afrag = *(const bf16x8*)ap;
        bf16x8 bfrag = wp[(wave * 4 + kc) * 64 + lane];
        oacc = __builtin_amdgcn_mfma_f32_16x16x32_bf16(afrag, bfrag, oacc, 0, 0, 0);
    }

    // ---- phase 3: bias + relu + store + fused segmax
    int col = wave * 16 + (lane & 15);
    int subrow = (lane >> 4) * 4;
    float bcol = bias[col];
#pragma unroll
    for (int i = 0; i < 4; ++i) {
        int r = subrow + i;
        float v = fmaxf(oacc[i] + bcol, 0.f);
        smx[r][col] = v;
        Hout[(size_t)(nbase + r) * 128 + col] = f2b(v);
    }
    __syncthreads();
    if (tid < 128) {
        int jj = 0;
        while (jj < 16) {
            int g = bb[jj];
            float m = smx[jj][tid];
            int k = jj + 1;
            while (k < 16 && bb[k] == g) { m = fmaxf(m, smx[k][tid]); ++k; }
            atomicMax((int*)&gbuf[g * GDIM + goff + tid], __float_as_int(m));
            jj = k;
        }
    }
}

// ---------------- final: out[G,128] = gbuf[G,640] @ Wa[640,128] + ba

__global__ __launch_bounds__(128) void k_final(const float* __restrict__ gbuf,
                                               const float* __restrict__ Wa,
                                               const float* __restrict__ ba,
                                               float* __restrict__ out) {
    __shared__ float gr[GDIM];
    int g = blockIdx.x, t = threadIdx.x;
    for (int i = t; i < GDIM; i += 128) gr[i] = gbuf[g * GDIM + i];
    __syncthreads();
    float acc = ba[t];
    for (int k = 0; k < GDIM; ++k) acc = fmaf(gr[k], Wa[k * 128 + t], acc);
    out[g * 128 + t] = acc;
}

// ---------------- launch ----------------

extern "C" void kernel_launch(void* const* d_in, const int* in_sizes, int n_in,
                              void* d_out, int out_size, void* d_ws, size_t ws_size,
                              hipStream_t stream) {
    const float* pos    = (const float*)d_in[0];
    const int*   idfeat = (const int*)d_in[1];
    const int*   eidx   = (const int*)d_in[2];
    const int*   batch  = (const int*)d_in[3];
    const float* Wp     = (const float*)d_in[5];
    const float* bp     = (const float*)d_in[6];
    const float* id_emb = (const float*)d_in[7];
    const float* Wn     = (const float*)d_in[8];
    const float* bn     = (const float*)d_in[9];
    const float* convW  = (const float*)d_in[10];
    const float* convb  = (const float*)d_in[11];
    const float* Wa     = (const float*)d_in[12];
    const float* ba     = (const float*)d_in[13];
    float* out = (float*)d_out;

    const int* esrc = eidx;
    const int* edst = eidx + N_EDGES;

    char* w = (char*)d_ws;
    auto alloc = [&](size_t bytes) -> char* {
        char* p = w;
        w += (bytes + 255) & ~(size_t)255;
        return p;
    };
    // cnt and gbuf adjacent -> single memset clears both
    int*   cnt  = (int*)alloc((size_t)N_NODES * 4);
    float* gbuf = (float*)alloc((size_t)NGRAPH * GDIM * 4);
    size_t zbytes = (((size_t)N_NODES * 4 + 255) & ~(size_t)255) + (size_t)NGRAPH * GDIM * 4;
    unsigned short* A16a = (unsigned short*)alloc((size_t)N_NODES * D * 2);
    unsigned short* A16b = (unsigned short*)alloc((size_t)N_NODES * D * 2);
    float* dinv = (float*)alloc((size_t)N_NODES * 4);
    int*   offs = (int*)alloc((size_t)(N_NODES + 1) * 4);
    int*   csum = (int*)alloc(64 * 4);
    int*   coff = (int*)alloc(64 * 4);
    int*   csrs = (int*)alloc((size_t)N_EDGES * 4);
    int*   ebuf = (int*)alloc((size_t)N_EDGES * 4);
    int*   btail= (int*)alloc((NBUCK + 1) * 4);
    int*   bstart=(int*)alloc((NBUCK + 1) * 4);
    float* T    = (float*)alloc((size_t)256 * D * 4);
    unsigned short* Wpack = (unsigned short*)alloc((size_t)5 * 16384 * 2);

    hipMemsetAsync(cnt, 0, zbytes, stream);

    k_count<<<(N_EDGES + 255) / 256, 256, 0, stream>>>(edst, cnt);

    int nchunk = (N_NODES + 1023) / 1024; // 49
    k_scanA<<<nchunk, 256, 0, stream>>>(cnt, offs, csum);
    k_scanB<<<1, 64, 0, stream>>>(csum, coff, nchunk);
    k_scanC<<<(N_NODES + 255) / 256, 256, 0, stream>>>(offs, coff, cnt, dinv, btail, bstart);

    k_bucket<<<(N_EDGES + 2047) / 2048, 256, 0, stream>>>(esrc, edst, btail, ebuf);
    k_fillB<<<NBUCK, 256, 0, stream>>>(ebuf, bstart, offs, csrs);

    k_prep<<<448, 256, 0, stream>>>(Wn, convW, Wpack, id_emb, T);
    k_encoder<<<(N_NODES + 63) / 64, 256, 0, stream>>>(pos, idfeat, Wp, bp, Wpack, bn, T,
                                                       A16a, batch, gbuf);

    unsigned short* Hin = A16a;
    unsigned short* Hout = A16b;
    for (int l = 0; l < NLAYER; ++l) {
        k_layer<<<N_NODES / 16, 512, 0, stream>>>(Hin, Hout, Wpack + (size_t)(l + 1) * 16384,
                                                  offs, cnt, csrs, dinv,
                                                  convb + (size_t)l * D, batch, gbuf,
                                                  (l + 1) * D);
        unsigned short* tmp = Hin; Hin = Hout; Hout = tmp;
    }

    k_final<<<NGRAPH, 128, 0, stream>>>(gbuf, Wa, ba, out);
}